// Round 1
// baseline (1429.437 us; speedup 1.0000x reference)
//
#include <hip/hip_runtime.h>
#include <math.h>

// GAT layer w/ edge features, f32 baseline.
// Decomposition: fold Wproj/Wattn into per-node precomputes + one fused
// per-edge GEMM [E,128]@[128,136]; CSR-based segment softmax (no float atomics).

constexpr int NN = 50000;
constexpr int NE = 600000;
constexpr int APAD = 132;   // A-tile row stride (pad 128 -> 132: 2-way banks, free)
constexpr int BSTR = 160;   // B-tile row: 16 col-groups * stride 10 (8 used + 2 pad)

// ---------------- weight combine ----------------
// Wec[i][c] = sum_k We[h][i][k]*Wproj[h][k][o]   (c = h*16+o)  -> edge GEMM B
// Ae [i][h] = sum_k We[h][i][k]*Wattn[h][k]                    -> attn cols
// Wn [i][c] = Wh[h][i][o]                                      -> node GEMM B
__global__ void k_combine(const float* __restrict__ Wh, const float* __restrict__ We,
                          const float* __restrict__ Wproj, const float* __restrict__ Wattn,
                          float* __restrict__ Wec, float* __restrict__ Ae, float* __restrict__ Wn)
{
    int tid = blockIdx.x * 256 + threadIdx.x;
    if (tid < 16384) {
        int i = tid >> 7, c = tid & 127;
        int h = c >> 4, o = c & 15;
        float s = 0.f;
#pragma unroll
        for (int k = 0; k < 16; ++k)
            s += We[h*2048 + i*16 + k] * Wproj[h*768 + k*16 + o];
        Wec[i*128 + c] = s;
    } else if (tid < 17408) {
        int q = tid - 16384;
        int i = q >> 3, h = q & 7;
        float s = 0.f;
#pragma unroll
        for (int k = 0; k < 16; ++k)
            s += We[h*2048 + i*16 + k] * Wattn[h*48 + k];
        Ae[i*8 + h] = s;
    } else if (tid < 33792) {
        int q = tid - 17408;
        int i = q >> 7, c = q & 127;
        int h = c >> 4, o = c & 15;
        Wn[i*128 + c] = Wh[h*2048 + i*16 + o];
    }
}

// ---------------- shared GEMM helpers (BM=128 rows, 512 threads) ----------------
__device__ __forceinline__ void stage_ab(const float* __restrict__ Aglob,
                                         const float* __restrict__ Bglob,
                                         float* Al, float* Bl, int m0, int M)
{
    int t = threadIdx.x;
    {   // A: coalesced float4 loads, row-major LDS w/ pad 132
        int r = t >> 2, kc = t & 3;
        int gr = m0 + r; if (gr >= M) gr = M - 1;   // clamp; stores masked later
        const float4* s4 = (const float4*)(Aglob + (size_t)gr*128 + kc*32);
        float4* d4 = (float4*)(Al + r*APAD + kc*32);
#pragma unroll
        for (int i = 0; i < 8; ++i) d4[i] = s4[i];
    }
    {   // B: [128][128] -> groups of 8 cols at stride 10 (conflict-free reads)
        const float2* B2 = (const float2*)Bglob;
#pragma unroll
        for (int it = 0; it < 16; ++it) {
            int q = it*512 + t;               // 8192 float2s
            int k = q >> 6, c2 = q & 63;
            int c = c2*2, g = c >> 3, j = c & 7;
            float2 v = B2[q];
            Bl[k*BSTR + g*10 + j]     = v.x;
            Bl[k*BSTR + g*10 + j + 1] = v.y;
        }
    }
}

__device__ __forceinline__ void mm_core(const float* Al, const float* Bl, float acc[4][8])
{
    int t = threadIdx.x;
    int rowg = t >> 4, colg = t & 15;
    int r0 = rowg * 4;
#pragma unroll
    for (int i = 0; i < 4; ++i)
#pragma unroll
        for (int j = 0; j < 8; ++j) acc[i][j] = 0.f;
#pragma unroll 4
    for (int k = 0; k < 128; ++k) {
        float a0 = Al[(r0+0)*APAD + k];
        float a1 = Al[(r0+1)*APAD + k];
        float a2 = Al[(r0+2)*APAD + k];
        float a3 = Al[(r0+3)*APAD + k];
        const float* bp = Bl + k*BSTR + colg*10;
#pragma unroll
        for (int j = 0; j < 8; ++j) {
            float b = bp[j];
            acc[0][j] += a0 * b;
            acc[1][j] += a1 * b;
            acc[2][j] += a2 * b;
            acc[3][j] += a3 * b;
        }
    }
}

// ---------------- node GEMM: z_h = h @ Wn ----------------
__global__ __launch_bounds__(512, 2) void k_node_gemm(const float* __restrict__ hg,
                                                      const float* __restrict__ Wn,
                                                      float* __restrict__ z_h)
{
    __shared__ float Al[128*APAD];
    __shared__ float Bl[128*BSTR];
    int m0 = blockIdx.x * 128;
    stage_ab(hg, Wn, Al, Bl, m0, NN);
    __syncthreads();
    float acc[4][8];
    mm_core(Al, Bl, acc);
    int t = threadIdx.x;
    int rowg = t >> 4, colg = t & 15, r0 = rowg*4;
#pragma unroll
    for (int i = 0; i < 4; ++i) {
        int gr = m0 + r0 + i;
        if (gr < NN) {
            float4* dp = (float4*)(z_h + (size_t)gr*128 + colg*8);
            dp[0] = make_float4(acc[i][0], acc[i][1], acc[i][2], acc[i][3]);
            dp[1] = make_float4(acc[i][4], acc[i][5], acc[i][6], acc[i][7]);
        }
    }
}

// ---------------- node post: p_s/p_d/a_s/a_d from z_h ----------------
__global__ __launch_bounds__(256) void k_nodepost(const float* __restrict__ z_h,
    const float* __restrict__ Wproj, const float* __restrict__ Wattn,
    float* __restrict__ p_s, float* __restrict__ p_d,
    float* __restrict__ a_s, float* __restrict__ a_d)
{
    __shared__ float Wps[16*128], Wpd[16*128], Was[128], Wad[128];
    __shared__ float z2[2*140];   // 2 nodes, head-stride 17 (conflict-free)
    int t = threadIdx.x;
    for (int q = t; q < 2048; q += 256) {
        int k = q >> 7, rest = q & 127, h = rest >> 4, o = rest & 15;
        Wps[q] = Wproj[h*768 + (16+k)*16 + o];
        Wpd[q] = Wproj[h*768 + (32+k)*16 + o];
    }
    if (t < 128) {
        int h = t >> 4, k = t & 15;
        Was[t] = Wattn[h*48 + 16 + k];
        Wad[t] = Wattn[h*48 + 32 + k];
    }
    int nh = t >> 7, rest = t & 127, hh = rest >> 4, oo = rest & 15;
    int n0 = blockIdx.x * 32;
    for (int it = 0; it < 16; ++it) {
        int n = n0 + it*2 + nh;
        __syncthreads();
        {   // stage z rows (k := oo)
            float v = 0.f;
            if (n < NN) v = z_h[(size_t)n*128 + hh*16 + oo];
            z2[nh*140 + hh*17 + oo] = v;
        }
        __syncthreads();
        if (n < NN) {
            const float* zz = z2 + nh*140 + hh*17;
            float ps = 0.f, pd = 0.f, as_ = 0.f, ad_ = 0.f;
#pragma unroll
            for (int k = 0; k < 16; ++k) {
                float zv = zz[k];
                ps  += zv * Wps[k*128 + hh*16 + oo];
                pd  += zv * Wpd[k*128 + hh*16 + oo];
                as_ += zv * Was[hh*16 + k];
                ad_ += zv * Wad[hh*16 + k];
            }
            p_s[(size_t)n*128 + rest] = ps;
            p_d[(size_t)n*128 + rest] = pd;
            if (oo == 0) { a_s[n*8 + hh] = as_; a_d[n*8 + hh] = ad_; }
        }
    }
}

// ---------------- edge GEMM + attn + e_out ----------------
__global__ __launch_bounds__(512, 2) void k_edge(const float* __restrict__ eg,
    const float* __restrict__ Wec, const float* __restrict__ Aeg,
    const float* __restrict__ bproj,
    const int* __restrict__ src, const int* __restrict__ dst,
    const float* __restrict__ p_s, const float* __restrict__ p_d,
    const float* __restrict__ a_s, const float* __restrict__ a_d,
    float* __restrict__ attn, float* __restrict__ e_out)
{
    __shared__ float Al[128*APAD];
    __shared__ float Bl[128*BSTR];
    __shared__ float Ael[128*8];
    __shared__ float bpl[128];
    int t = threadIdx.x;
    int m0 = blockIdx.x * 128;
    stage_ab(eg, Wec, Al, Bl, m0, NE);
    for (int q = t; q < 1024; q += 512) Ael[q] = Aeg[q];
    if (t < 128) bpl[t] = bproj[t];
    __syncthreads();
    float acc[4][8];
    mm_core(Al, Bl, acc);

    // attn: thread -> (row r = t>>2, head pair hp = t&3)
    {
        int hp = t & 3, r = t >> 2;
        int er = m0 + r;
        if (er < NE) {
            float s0 = 0.f, s1 = 0.f;
#pragma unroll 4
            for (int k = 0; k < 128; ++k) {
                float a = Al[r*APAD + k];
                s0 += a * Ael[k*8 + 2*hp];
                s1 += a * Ael[k*8 + 2*hp + 1];
            }
            int sj = src[er], dj = dst[er];
            float v0 = s0 + a_s[sj*8 + 2*hp]     + a_d[dj*8 + 2*hp];
            float v1 = s1 + a_s[sj*8 + 2*hp + 1] + a_d[dj*8 + 2*hp + 1];
            v0 = v0 > 0.f ? v0 : 0.01f * v0;     // leaky_relu, slope 0.01
            v1 = v1 > 0.f ? v1 : 0.01f * v1;
            ((float2*)(attn + (size_t)er*8 + 2*hp))[0] = make_float2(v0, v1);
        }
    }

    // e_out = e + elu(acc + p_s[src] + p_d[dst] + bproj); e residual read from LDS A-tile
    int rowg = t >> 4, colg = t & 15, r0 = rowg*4;
#pragma unroll
    for (int i = 0; i < 4; ++i) {
        int er = m0 + r0 + i;
        if (er < NE) {
            int sj = src[er], dj = dst[er];
            const float* psp = p_s + (size_t)sj*128 + colg*8;
            const float* pdp = p_d + (size_t)dj*128 + colg*8;
            float outv[8];
#pragma unroll
            for (int j = 0; j < 8; ++j) {
                int c = colg*8 + j;
                float val = acc[i][j] + psp[j] + pdp[j] + bpl[c];
                float el = val > 0.f ? val : expm1f(val);
                outv[j] = Al[(r0+i)*APAD + c] + el;
            }
            float4* op = (float4*)(e_out + (size_t)er*128 + colg*8);
            op[0] = make_float4(outv[0], outv[1], outv[2], outv[3]);
            op[1] = make_float4(outv[4], outv[5], outv[6], outv[7]);
        }
    }
}

// ---------------- CSR build ----------------
__global__ void k_hist(const int* __restrict__ dst, int* __restrict__ deg)
{
    int e = blockIdx.x*256 + threadIdx.x;
    if (e < NE) atomicAdd(&deg[dst[e]], 1);
}

__global__ __launch_bounds__(1024) void k_scan1(const int* __restrict__ deg,
                                                int* __restrict__ offs, int* __restrict__ bsum)
{
    __shared__ int s[1024];
    int t = threadIdx.x;
    int idx = blockIdx.x*1024 + t;
    int v = (idx < NN) ? deg[idx] : 0;
    s[t] = v;
    __syncthreads();
    for (int off = 1; off < 1024; off <<= 1) {
        int x = (t >= off) ? s[t - off] : 0;
        __syncthreads();
        s[t] += x;
        __syncthreads();
    }
    if (idx < NN) offs[idx] = s[t] - v;       // exclusive within block
    if (t == 1023) bsum[blockIdx.x] = s[1023];
}

__global__ void k_scan2(const int* __restrict__ bsum, int* __restrict__ bases)
{
    int i = threadIdx.x;                      // 64 threads, 49 sums
    int v = (i < 49) ? bsum[i] : 0;
    int incl = v;
#pragma unroll
    for (int off = 1; off < 64; off <<= 1) {
        int x = __shfl_up(incl, off, 64);
        if (i >= off) incl += x;
    }
    if (i < 49) bases[i] = incl - v;
}

__global__ void k_scan3(int* __restrict__ offs, const int* __restrict__ bases,
                        int* __restrict__ cursor)
{
    int n = blockIdx.x*256 + threadIdx.x;
    if (n < NN) {
        int v = offs[n] + bases[n >> 10];
        offs[n] = v;
        cursor[n] = v;
    }
}

__global__ void k_scatter(const int* __restrict__ dst, int* __restrict__ cursor,
                          int* __restrict__ eids)
{
    int e = blockIdx.x*256 + threadIdx.x;
    if (e < NE) {
        int p = atomicAdd(&cursor[dst[e]], 1);
        eids[p] = e;
    }
}

// ---------------- per-node segment softmax + aggregate ----------------
// 256 threads = 2 nodes; per node 128 threads (h = t>>4, o = t&15); no LDS/barriers.
__global__ __launch_bounds__(256) void k_agg(const float* __restrict__ hg,
    const float* __restrict__ z_h, const float* __restrict__ attn,
    const int* __restrict__ eids, const int* __restrict__ offs, const int* __restrict__ deg,
    const int* __restrict__ src, float* __restrict__ h_out)
{
    int half = threadIdx.x >> 7;
    int t = threadIdx.x & 127;
    int n = blockIdx.x * 2 + half;
    int hh = t >> 4;
    int dg = deg[n];
    int o0 = offs[n];
    float m = -INFINITY;
    for (int j = (t & 15); j < dg; j += 16) {
        int e = eids[o0 + j];
        m = fmaxf(m, attn[(size_t)e*8 + hh]);
    }
#pragma unroll
    for (int s = 1; s < 16; s <<= 1) m = fmaxf(m, __shfl_xor(m, s, 64));
    float denom = 0.f, num = 0.f;
    for (int j = 0; j < dg; ++j) {
        int e = eids[o0 + j];
        float ex = expf(attn[(size_t)e*8 + hh] - m);
        denom += ex;                                   // identical across the 16-lane group
        num += ex * z_h[(size_t)src[e]*128 + t];       // coalesced 512B row gather
    }
    float hag = num / fmaxf(denom, 1e-9f);
    float el = hag > 0.f ? hag : expm1f(hag);
    h_out[(size_t)n*128 + t] = hg[(size_t)n*128 + t] + el;
}

// ---------------- launcher ----------------
extern "C" void kernel_launch(void* const* d_in, const int* in_sizes, int n_in,
                              void* d_out, int out_size, void* d_ws, size_t ws_size,
                              hipStream_t stream)
{
    const float* h     = (const float*)d_in[0];
    const float* e     = (const float*)d_in[1];
    const int*   src   = (const int*)d_in[2];
    const int*   dst   = (const int*)d_in[3];
    const float* Wh    = (const float*)d_in[4];
    const float* We    = (const float*)d_in[5];
    const float* Wproj = (const float*)d_in[6];
    const float* bproj = (const float*)d_in[7];
    const float* Wattn = (const float*)d_in[8];
    float* h_out = (float*)d_out;
    float* e_out = h_out + (size_t)NN * 128;

    char* w = (char*)d_ws;
    auto alloc = [&](size_t bytes) {
        char* p = w;
        w += (bytes + 255) & ~(size_t)255;
        return p;
    };
    float* Wec  = (float*)alloc(16384 * 4);
    float* Ae   = (float*)alloc(1024 * 4);
    float* Wn   = (float*)alloc(16384 * 4);
    float* z_h  = (float*)alloc((size_t)NN * 128 * 4);
    float* p_s  = (float*)alloc((size_t)NN * 128 * 4);
    float* p_d  = (float*)alloc((size_t)NN * 128 * 4);
    float* a_s  = (float*)alloc((size_t)NN * 8 * 4);
    float* a_d  = (float*)alloc((size_t)NN * 8 * 4);
    float* attn = (float*)alloc((size_t)NE * 8 * 4);
    int* deg    = (int*)alloc((size_t)NN * 4);
    int* offs   = (int*)alloc((size_t)NN * 4);
    int* cursor = (int*)alloc((size_t)NN * 4);
    int* eids   = (int*)alloc((size_t)NE * 4);
    int* bsum   = (int*)alloc(64 * 4);
    int* bases  = (int*)alloc(64 * 4);
    // total ws use ~103 MB

    hipMemsetAsync(deg, 0, (size_t)NN * 4, stream);

    k_combine<<<132, 256, 0, stream>>>(Wh, We, Wproj, Wattn, Wec, Ae, Wn);
    k_node_gemm<<<(NN + 127) / 128, 512, 0, stream>>>(h, Wn, z_h);
    k_nodepost<<<(NN + 31) / 32, 256, 0, stream>>>(z_h, Wproj, Wattn, p_s, p_d, a_s, a_d);
    k_edge<<<(NE + 127) / 128, 512, 0, stream>>>(e, Wec, Ae, bproj, src, dst,
                                                 p_s, p_d, a_s, a_d, attn, e_out);
    k_hist<<<(NE + 255) / 256, 256, 0, stream>>>(dst, deg);
    k_scan1<<<49, 1024, 0, stream>>>(deg, offs, bsum);
    k_scan2<<<1, 64, 0, stream>>>(bsum, bases);
    k_scan3<<<(NN + 255) / 256, 256, 0, stream>>>(offs, bases, cursor);
    k_scatter<<<(NE + 255) / 256, 256, 0, stream>>>(dst, cursor, eids);
    k_agg<<<NN / 2, 256, 0, stream>>>(h, z_h, attn, eids, offs, deg, src, h_out);
}